// Round 5
// baseline (227.377 us; speedup 1.0000x reference)
//
#include <hip/hip_runtime.h>
#include <cmath>

// FSEncLoss on gfx950 — split-phase experiment.
// loss = mean over (block, c) of [ softplus(x) - t*x ],
//   t = 1 iff class c appears in the 8x8 target block.
// B=16, H=1024, W=2048, G=8, NUM_CLASSES=19.
//
// R4 post-mortem: fused kernel stuck at ~70us (~2.5 TB/s effective) across two
// structures; harness fills hit 6.9 TB/s. Split into two pure streams to
// isolate (and hopefully fix) the latency-capped read path:
//   Kernel A: targets (134 MB, coalesced int4 x8) -> per-block 19-bit mask
//             -> d_ws (524288 x u32 = 2 MB). No LDS, no barrier.
//   Kernel B: preds (40 MB, grid-stride float4) + magic-div /19 + mask gather
//             (2 MB, L2-resident) -> softplus - t*x -> reduce -> one atomic.
// Global block index: blk = wg*128 + j (wg = 8-row x 1024-col strip, j = t>>1)
// matches preds row-major block order exactly.

typedef float f4a __attribute__((vector_size(16), aligned(16)));

__global__ __launch_bounds__(256) void fsenc_mask_kernel(
    const int* __restrict__ targets,
    unsigned*  __restrict__ masks,
    int H, int W)
{
    const int t  = threadIdx.x;
    const int wg = blockIdx.x;

    const int strips_per_row = W / 1024;          // 2
    const int rows_per_img   = H / 8;             // 128
    const int block_row = wg / strips_per_row;
    const int strip     = wg % strips_per_row;
    const int b_img = block_row / rows_per_img;
    const int bh    = block_row % rows_per_img;
    const int col0  = strip * 1024;

    const int4* tgt4 = (const int4*)targets;
    const long row_stride4 = (long)W / 4;
    const long tbase = ((long)(b_img * H + bh * 8) * W + col0) / 4 + t;

    int4 tv[8];
    #pragma unroll
    for (int r = 0; r < 8; ++r)
        tv[r] = tgt4[tbase + (long)r * row_stride4];

    unsigned mask = 0u;
    #pragma unroll
    for (int r = 0; r < 8; ++r)
        mask |= (1u << tv[r].x) | (1u << tv[r].y) | (1u << tv[r].z) | (1u << tv[r].w);
    mask |= __shfl_xor(mask, 1);      // lanes {2j,2j+1} -> block j's full mask

    if ((t & 1) == 0)
        masks[wg * 128 + (t >> 1)] = mask;   // blk_global = wg*128 + j
}

__global__ __launch_bounds__(256) void fsenc_loss_kernel(
    const float*    __restrict__ preds,
    const unsigned* __restrict__ masks,
    float*          __restrict__ out,
    int n_vec4,            // 2490368 = 524288*19/4
    float inv_count)
{
    const int tid    = blockIdx.x * 256 + threadIdx.x;
    const int stride = gridDim.x * 256;

    float acc = 0.f;
    for (int i = tid; i < n_vec4; i += stride) {
        f4a v = *(const f4a*)(preds + 4 * (long)i);
        const unsigned l0 = 4u * (unsigned)i;
        #pragma unroll
        for (int k = 0; k < 4; ++k) {
            unsigned l   = l0 + (unsigned)k;
            // l/19 via magic mul: valid for l < 330M (l_max = 9961471)
            unsigned blk = (unsigned)(((unsigned long long)l * 226050911ull) >> 32);
            unsigned c   = l - blk * 19u;
            float x  = v[k];
            float sp = fmaxf(x, 0.f) + __logf(1.f + __expf(-fabsf(x)));
            acc += sp - (float)((masks[blk] >> c) & 1u) * x;
        }
    }

    #pragma unroll
    for (int off = 32; off; off >>= 1)
        acc += __shfl_down(acc, off);

    __shared__ float s_part[4];
    if ((threadIdx.x & 63) == 0) s_part[threadIdx.x >> 6] = acc;
    __syncthreads();
    if (threadIdx.x == 0) {
        float tot = s_part[0] + s_part[1] + s_part[2] + s_part[3];
        atomicAdd(out, tot * inv_count);
    }
}

extern "C" void kernel_launch(void* const* d_in, const int* in_sizes, int n_in,
                              void* d_out, int out_size, void* d_ws, size_t ws_size,
                              hipStream_t stream) {
    const float* preds   = (const float*)d_in[0];
    const int*   targets = (const int*)d_in[1];
    float*       out     = (float*)d_out;
    unsigned*    masks   = (unsigned*)d_ws;      // 524288 * 4B = 2 MB scratch

    const int B = 16, H = 1024, W = 2048;
    const float inv_count = 1.0f / (float)in_sizes[0];   // n_blocks * 19
    const int n_vec4 = in_sizes[0] / 4;                  // 2490368

    (void)hipMemsetAsync(out, 0, sizeof(float), stream);

    const int gridA = B * (H / 8) * (W / 1024);   // 4096 workgroups
    fsenc_mask_kernel<<<gridA, 256, 0, stream>>>(targets, masks, H, W);

    const int gridB = 1024;                        // 262144 threads, ~9.5 f4/thread
    fsenc_loss_kernel<<<gridB, 256, 0, stream>>>(preds, masks, out,
                                                 n_vec4, inv_count);
}

// Round 6
// 216.683 us; speedup vs baseline: 1.0494x; 1.0494x over previous
//
#include <hip/hip_runtime.h>
#include <cmath>

// FSEncLoss on gfx950 — single fused kernel, band-contiguous, NT loads.
// loss = mean over (block, c) of [ softplus(x) - t*x ],
//   t = 1 iff class c appears in the 8x8 target block.
// B=16, H=1024, W=2048, G=8, NUM_CLASSES=19.
//
// Read-ceiling theory (R5): reads capped at ~2.5 TB/s by per-CU outstanding-
// miss slots x ~850ns latency. Levers: (a) nontemporal loads (bypass L1
// miss tracking), (b) contiguous per-WG footprint for DRAM row locality.
//
// Workgroup = one band of 8 rows x 2048 cols = 64KB targets CONTIGUOUS
// + 256 blocks whose preds are 19456B CONTIGUOUS.
// Thread t: 16 int4 target loads (row r: chunks t and t+256; chunk t covers
// cols 4t..4t+3 -> strip-block t>>1; chunk t+256 -> strip-block 128+(t>>1)).
// Lane pair {2j,2j+1} -> shfl_xor(1) merges to full masks of blocks j (m0)
// and 128+j (m1). Preds: blockA = band*256 + (t>>1), blockB = blockA+128;
// even lane computes classes 0-7 of A and B, odd lane classes 8-18.
// All ~20-22 loads per thread independent; no barrier until final reduce.

typedef int   i4v __attribute__((ext_vector_type(4), aligned(16)));
typedef float f4u __attribute__((ext_vector_type(4), aligned(4)));

__global__ __launch_bounds__(256) void fsenc_loss_kernel(
    const float* __restrict__ preds,
    const int*   __restrict__ targets,
    float*       __restrict__ out,
    float inv_count)
{
    const int t    = threadIdx.x;
    const int band = blockIdx.x;               // 2048 bands (B*H/8)

    // ---- targets: contiguous 64KB band, 16 independent NT int4 loads ----
    const i4v* tb = (const i4v*)targets + (long)band * 4096;  // 4096 i4/band
    i4v tv[16];
    #pragma unroll
    for (int r = 0; r < 8; ++r) {
        tv[2*r]   = __builtin_nontemporal_load(tb + r * 512 + t);
        tv[2*r+1] = __builtin_nontemporal_load(tb + r * 512 + t + 256);
    }

    // ---- preds: blocks band*256+(t>>1) and +128, NT float4 loads ----
    const long blockA = (long)band * 256 + (t >> 1);
    const float* pA = preds + blockA * 19;
    const float* pB = pA + 128 * 19;
    f4u a0 = {0.f,0.f,0.f,0.f}, a1 = a0, a2 = a0, b0 = a0, b1 = a0, b2 = a0;
    if ((t & 1) == 0) {
        a0 = __builtin_nontemporal_load((const f4u*)(pA + 0));
        a1 = __builtin_nontemporal_load((const f4u*)(pA + 4));
        b0 = __builtin_nontemporal_load((const f4u*)(pB + 0));
        b1 = __builtin_nontemporal_load((const f4u*)(pB + 4));
    } else {
        a0 = __builtin_nontemporal_load((const f4u*)(pA + 8));
        a1 = __builtin_nontemporal_load((const f4u*)(pA + 12));
        a2 = __builtin_nontemporal_load((const f4u*)(pA + 15));  // use [1..3]
        b0 = __builtin_nontemporal_load((const f4u*)(pB + 8));
        b1 = __builtin_nontemporal_load((const f4u*)(pB + 12));
        b2 = __builtin_nontemporal_load((const f4u*)(pB + 15));  // use [1..3]
    }

    // ---- masks ----
    unsigned m0 = 0u, m1 = 0u;
    #pragma unroll
    for (int r = 0; r < 8; ++r) {
        i4v u = tv[2*r], w = tv[2*r+1];
        m0 |= (1u << u[0]) | (1u << u[1]) | (1u << u[2]) | (1u << u[3]);
        m1 |= (1u << w[0]) | (1u << w[1]) | (1u << w[2]) | (1u << w[3]);
    }
    m0 |= __shfl_xor(m0, 1);          // block j   = blockA full mask
    m1 |= __shfl_xor(m1, 1);          // block j+128 = blockB full mask

    // ---- softplus(x) - t*x ----
    float acc = 0.f;
    #define SP_TERM(xval, msk, cls)                                            \
        {                                                                      \
            float x_ = (xval);                                                 \
            float sp_ = fmaxf(x_, 0.f) + __logf(1.f + __expf(-fabsf(x_)));     \
            acc += sp_ - (float)(((msk) >> (cls)) & 1u) * x_;                  \
        }
    if ((t & 1) == 0) {
        SP_TERM(a0[0], m0, 0)  SP_TERM(a0[1], m0, 1)  SP_TERM(a0[2], m0, 2)  SP_TERM(a0[3], m0, 3)
        SP_TERM(a1[0], m0, 4)  SP_TERM(a1[1], m0, 5)  SP_TERM(a1[2], m0, 6)  SP_TERM(a1[3], m0, 7)
        SP_TERM(b0[0], m1, 0)  SP_TERM(b0[1], m1, 1)  SP_TERM(b0[2], m1, 2)  SP_TERM(b0[3], m1, 3)
        SP_TERM(b1[0], m1, 4)  SP_TERM(b1[1], m1, 5)  SP_TERM(b1[2], m1, 6)  SP_TERM(b1[3], m1, 7)
    } else {
        SP_TERM(a0[0], m0, 8)  SP_TERM(a0[1], m0, 9)  SP_TERM(a0[2], m0, 10) SP_TERM(a0[3], m0, 11)
        SP_TERM(a1[0], m0, 12) SP_TERM(a1[1], m0, 13) SP_TERM(a1[2], m0, 14) SP_TERM(a1[3], m0, 15)
        SP_TERM(a2[1], m0, 16) SP_TERM(a2[2], m0, 17) SP_TERM(a2[3], m0, 18)
        SP_TERM(b0[0], m1, 8)  SP_TERM(b0[1], m1, 9)  SP_TERM(b0[2], m1, 10) SP_TERM(b0[3], m1, 11)
        SP_TERM(b1[0], m1, 12) SP_TERM(b1[1], m1, 13) SP_TERM(b1[2], m1, 14) SP_TERM(b1[3], m1, 15)
        SP_TERM(b2[1], m1, 16) SP_TERM(b2[2], m1, 17) SP_TERM(b2[3], m1, 18)
    }
    #undef SP_TERM

    // ---- reduce: wave (64) -> workgroup -> one atomic ----
    #pragma unroll
    for (int off = 32; off; off >>= 1)
        acc += __shfl_down(acc, off);

    __shared__ float s_part[4];
    if ((t & 63) == 0) s_part[t >> 6] = acc;
    __syncthreads();
    if (t == 0) {
        float tot = s_part[0] + s_part[1] + s_part[2] + s_part[3];
        atomicAdd(out, tot * inv_count);
    }
}

extern "C" void kernel_launch(void* const* d_in, const int* in_sizes, int n_in,
                              void* d_out, int out_size, void* d_ws, size_t ws_size,
                              hipStream_t stream) {
    const float* preds   = (const float*)d_in[0];
    const int*   targets = (const int*)d_in[1];
    float*       out     = (float*)d_out;

    const int B = 16, H = 1024;
    const float inv_count = 1.0f / (float)in_sizes[0];   // n_blocks * 19

    (void)hipMemsetAsync(out, 0, sizeof(float), stream);

    const int grid = B * (H / 8);                 // 2048 bands
    fsenc_loss_kernel<<<grid, 256, 0, stream>>>(preds, targets, out, inv_count);
}

// Round 7
// 215.536 us; speedup vs baseline: 1.0549x; 1.0053x over previous
//
#include <hip/hip_runtime.h>
#include <cmath>

// FSEncLoss on gfx950 — uniform-stream fused kernel (no branches, no shfl).
// loss = mean over (block, c) of [ softplus(x) - t*x ],
//   t = 1 iff class c appears in the 8x8 target block.
// B=16, H=1024, W=2048, G=8, NUM_CLASSES=19.
//
// R6 model: demand reads capped ~2.7 TB/s by per-CU outstanding-line slots x
// ~850ns latency (fills hit 6.9 TB/s because writes are posted). This round
// removes the last software confound: lane specialization. One thread = one
// 8x8 block:
//   targets: 16 NT int4 loads (rows r=0..7, chunks 2t, 2t+1); per row the
//            wave touches 2KB contiguous; whole WG band = 64KB contiguous.
//   preds:   own block's 19 floats via 5 NT float4 loads at p+{0,4,8,12,15}
//            (q3 covers classes 12-15, q4[1..3] covers 16-18).
// 21 independent loads/thread, straight-line body, no divergence, no shfl,
// no barrier until the final 4-partial reduce.

typedef int   i4v __attribute__((ext_vector_type(4), aligned(16)));
typedef float f4u __attribute__((ext_vector_type(4), aligned(4)));

__global__ __launch_bounds__(256) void fsenc_loss_kernel(
    const float* __restrict__ preds,
    const int*   __restrict__ targets,
    float*       __restrict__ out,
    float inv_count)
{
    const int t    = threadIdx.x;
    const int band = blockIdx.x;               // 2048 bands (B*H/8)

    // ---- targets: thread t owns block t of the band (cols 8t..8t+7) ----
    const i4v* tb = (const i4v*)targets + (long)band * 4096;  // 4096 i4/band
    i4v tv[16];
    #pragma unroll
    for (int r = 0; r < 8; ++r) {
        tv[2*r]   = __builtin_nontemporal_load(tb + r * 512 + 2*t);
        tv[2*r+1] = __builtin_nontemporal_load(tb + r * 512 + 2*t + 1);
    }

    // ---- preds: own block's 19 floats, 5 overlapping NT float4 loads ----
    const float* p = preds + ((long)band * 256 + t) * 19;
    f4u q0 = __builtin_nontemporal_load((const f4u*)(p + 0));
    f4u q1 = __builtin_nontemporal_load((const f4u*)(p + 4));
    f4u q2 = __builtin_nontemporal_load((const f4u*)(p + 8));
    f4u q3 = __builtin_nontemporal_load((const f4u*)(p + 12));
    f4u q4 = __builtin_nontemporal_load((const f4u*)(p + 15));  // [1..3]=c16..18

    // ---- presence mask ----
    unsigned m = 0u;
    #pragma unroll
    for (int i = 0; i < 16; ++i) {
        i4v u = tv[i];
        m |= (1u << u[0]) | (1u << u[1]) | (1u << u[2]) | (1u << u[3]);
    }

    // ---- softplus(x) - t*x over all 19 classes ----
    float acc = 0.f;
    #define SP_TERM(xval, cls)                                                 \
        {                                                                      \
            float x_ = (xval);                                                 \
            float sp_ = fmaxf(x_, 0.f) + __logf(1.f + __expf(-fabsf(x_)));     \
            acc += sp_ - (float)((m >> (cls)) & 1u) * x_;                      \
        }
    SP_TERM(q0[0], 0)  SP_TERM(q0[1], 1)  SP_TERM(q0[2], 2)  SP_TERM(q0[3], 3)
    SP_TERM(q1[0], 4)  SP_TERM(q1[1], 5)  SP_TERM(q1[2], 6)  SP_TERM(q1[3], 7)
    SP_TERM(q2[0], 8)  SP_TERM(q2[1], 9)  SP_TERM(q2[2], 10) SP_TERM(q2[3], 11)
    SP_TERM(q3[0], 12) SP_TERM(q3[1], 13) SP_TERM(q3[2], 14) SP_TERM(q3[3], 15)
    SP_TERM(q4[1], 16) SP_TERM(q4[2], 17) SP_TERM(q4[3], 18)
    #undef SP_TERM

    // ---- reduce: wave (64) -> workgroup -> one atomic ----
    #pragma unroll
    for (int off = 32; off; off >>= 1)
        acc += __shfl_down(acc, off);

    __shared__ float s_part[4];
    if ((t & 63) == 0) s_part[t >> 6] = acc;
    __syncthreads();
    if (t == 0) {
        float tot = s_part[0] + s_part[1] + s_part[2] + s_part[3];
        atomicAdd(out, tot * inv_count);
    }
}

extern "C" void kernel_launch(void* const* d_in, const int* in_sizes, int n_in,
                              void* d_out, int out_size, void* d_ws, size_t ws_size,
                              hipStream_t stream) {
    const float* preds   = (const float*)d_in[0];
    const int*   targets = (const int*)d_in[1];
    float*       out     = (float*)d_out;

    const int B = 16, H = 1024;
    const float inv_count = 1.0f / (float)in_sizes[0];   // n_blocks * 19

    (void)hipMemsetAsync(out, 0, sizeof(float), stream);

    const int grid = B * (H / 8);                 // 2048 bands
    fsenc_loss_kernel<<<grid, 256, 0, stream>>>(preds, targets, out, inv_count);
}